// Round 7
// baseline (191.028 us; speedup 1.0000x reference)
//
#include <hip/hip_runtime.h>
#include <cstddef>
#include <cstdint>

// CollectMerge: x (B, P*CO, HI, WI) fp32, loc (B, 2P, HO, WO) fp32, bias (CO) fp32
// -> out (B, CO, HO, WO) fp32. Bilinear-sample each of P planes at loc, sum over P, + bias.
constexpr int B_  = 4;
constexpr int CO_ = 80;
constexpr int PN_ = 9;
constexpr int HI_ = 128;
constexpr int WI_ = 128;
constexpr int HW_ = HI_ * WI_;   // 16384

constexpr int NTHR   = 320;                  // 5 waves
constexpr int THW    = 128;                  // hw positions per transpose unit
constexpr int TUNITS = PN_ * (HW_ / THW);    // 1152 per batch
constexpr int GPX    = 32;                   // output pixels per gather unit
constexpr int GUNITS = HW_ / GPX;            // 512 per batch
// 512 : 1152 = 4 : 9 -> 13-block groups in mixed kernels

// LDS union: transpose tile (21760 B) vs gather tables+staging (19584 B).
union SMU {
    uint16_t tile[CO_][136];                 // T: 16B-aligned rows, 272B stride
    struct {
        float wts[PN_][GPX][4];              //  4608 B
        int   offs[PN_][GPX][4];             //  4608 B
        float accs[GPX][81];                 // 10368 B (odd stride)
    } g;
};

__device__ __forceinline__ uint16_t f2bf(float f) {
    uint32_t u = __float_as_uint(f);
    return (uint16_t)((u + 0x7fffu + ((u >> 16) & 1u)) >> 16);   // RNE
}

// Transpose+downconvert one (b, p, 128-hw chunk): x fp32 channel-major ->
// xt (plane, hw, co) bf16 channel-last. Same unit as the r2 kernel (COP=80).
__device__ __forceinline__ void t_unit(const float* __restrict__ x,
                                       uint16_t* __restrict__ xt,
                                       int b, int u, SMU* sm, int tid) {
    const int p   = u >> 7;                  // u / 128
    const int hw0 = (u & 127) << 7;          // (u % 128) * 128
    const size_t plane = (size_t)(b * PN_ + p);

    const float* src = x + plane * CO_ * (size_t)HW_ + hw0;
    for (int i = tid; i < CO_ * 32; i += NTHR) {        // 2560 float4, 8/thread
        const int co = i >> 5;
        const int h4 = (i & 31) << 2;
        const float4 v = *(const float4*)(src + (size_t)co * HW_ + h4);
        ushort4 pk;
        pk.x = f2bf(v.x); pk.y = f2bf(v.y); pk.z = f2bf(v.z); pk.w = f2bf(v.w);
        *(ushort4*)&sm->tile[co][h4] = pk;
    }
    __syncthreads();
    uint32_t* dst = (uint32_t*)(xt + (plane * HW_ + hw0) * CO_);
    for (int i = tid; i < THW * (CO_ / 8); i += NTHR) { // 1280 dwordx4, 4/thread
        const int px = i / 10;
        const int cp = i - px * 10;
        uint4 wv;
        uint32_t* w = (uint32_t*)&wv;
#pragma unroll
        for (int j = 0; j < 4; ++j) {
            const uint32_t lo = sm->tile[cp * 8 + 2 * j][px];
            const uint32_t hi = sm->tile[cp * 8 + 2 * j + 1][px];
            w[j] = lo | (hi << 16);
        }
        *(uint4*)(dst + px * 40 + cp * 4) = wv;
    }
}

// Gather+merge one (b, 32-px chunk) from bf16 channel-last xt. Exact r2 structure.
__device__ __forceinline__ void g_unit(const uint16_t* __restrict__ xt,
                                       const float* __restrict__ loc,
                                       const float* __restrict__ bias,
                                       float* __restrict__ out,
                                       int b, int u, SMU* sm, int tid) {
    const int hw0 = u * GPX;

    // Phase A: bilinear weights + premultiplied byte offsets per (p, pixel)
    if (tid < PN_ * GPX) {                               // 288
        const int p    = tid >> 5;
        const int pixl = tid & 31;
        const float y = loc[(((size_t)b * PN_ + p) * 2 + 0) * HW_ + hw0 + pixl];
        const float x = loc[(((size_t)b * PN_ + p) * 2 + 1) * HW_ + hw0 + pixl];
        const float y0f = floorf(y), x0f = floorf(x);
        const int   y0 = (int)y0f,  x0 = (int)x0f;
        const float dy = y - y0f,   dx = x - x0f;
        const float w[4] = { (1.f - dy) * (1.f - dx), (1.f - dy) * dx,
                             dy * (1.f - dx),         dy * dx };
#pragma unroll
        for (int c = 0; c < 4; ++c) {
            const int yi = y0 + (c >> 1);
            const int xi = x0 + (c & 1);
            const bool valid = (yi >= 0) & (yi < HI_) & (xi >= 0) & (xi < WI_);
            const int yc = min(max(yi, 0), HI_ - 1);
            const int xc = min(max(xi, 0), WI_ - 1);
            sm->g.wts[p][pixl][c]  = valid ? w[c] : 0.f;
            sm->g.offs[p][pixl][c] = (yc * WI_ + xc) * (CO_ * 2);   // byte offset
        }
    }
    __syncthreads();

    // Phase B: thread (pixl, cg): pixel pixl, channels cg*8..cg*8+7, 16B load per tap
    const int pixl = tid / 10;
    const int cg   = tid - pixl * 10;

    float acc[8];
#pragma unroll
    for (int j = 0; j < 8; ++j) acc[j] = bias[cg * 8 + j];

    for (int p = 0; p < PN_; ++p) {
        const char* base = (const char*)(xt + ((size_t)b * PN_ + p) * (size_t)HW_ * CO_)
                           + cg * 16;
        uint4 v[4]; float w[4];
#pragma unroll
        for (int c = 0; c < 4; ++c) {
            v[c] = *(const uint4*)(base + sm->g.offs[p][pixl][c]);
            w[c] = sm->g.wts[p][pixl][c];
        }
#pragma unroll
        for (int c = 0; c < 4; ++c) {
            const uint32_t* uu = (const uint32_t*)&v[c];
#pragma unroll
            for (int j = 0; j < 4; ++j) {
                acc[2*j]   = fmaf(__uint_as_float(uu[j] << 16),         w[c], acc[2*j]);
                acc[2*j+1] = fmaf(__uint_as_float(uu[j] & 0xffff0000u), w[c], acc[2*j+1]);
            }
        }
    }

#pragma unroll
    for (int j = 0; j < 8; ++j) sm->g.accs[pixl][cg * 8 + j] = acc[j];
    __syncthreads();

    // Phase C: coalesced channel-major write
    for (int i = tid; i < GPX * CO_; i += NTHR) {        // 8/thread
        const int co  = i >> 5;
        const int hwl = i & 31;
        out[((size_t)b * CO_ + co) * HW_ + hw0 + hwl] = sm->g.accs[hwl][co];
    }
}

// ---------------------------------------------------------------------------
// Pipeline kernels: tb = batch to transpose (-1 none), gb = batch to gather
// (-1 none). Mixed kernels interleave 4 G + 9 T blocks per 13 (G first:
// long poles start early). T and G parts are independent (G reads xt written
// by the PREVIOUS kernel; stream order guarantees visibility). T streams HBM
// while G chews L2 BW -> overlap of disjoint resources.
// ---------------------------------------------------------------------------
__global__ __launch_bounds__(NTHR) void pipe_k(const float* __restrict__ x,
                                               const float* __restrict__ loc,
                                               const float* __restrict__ bias,
                                               float* __restrict__ out,
                                               uint16_t* __restrict__ xt,
                                               int tb, int gb) {
    __shared__ SMU sm;
    const int bid = blockIdx.x;
    const int tid = threadIdx.x;

    if (gb < 0) { t_unit(x, xt, tb, bid, &sm, tid); return; }
    if (tb < 0) { g_unit(xt, loc, bias, out, gb, bid, &sm, tid); return; }
    const int grp = bid / 13;
    const int r   = bid - grp * 13;
    if (r < 4) g_unit(xt, loc, bias, out, gb, grp * 4 + r, &sm, tid);
    else       t_unit(x, xt, tb, grp * 9 + (r - 4), &sm, tid);
}

// ---------------------------------------------------------------------------
// Fallback (workspace too small): direct fp32 gather on original layout.
// ---------------------------------------------------------------------------
__global__ __launch_bounds__(256) void gather_direct_k(const float* __restrict__ xsrc,
                                                       const float* __restrict__ loc,
                                                       const float* __restrict__ bias,
                                                       float* __restrict__ out) {
    const int b   = blockIdx.x >> 10;
    const int hw0 = (blockIdx.x & 1023) << 4;
    const int tid = threadIdx.x;

    __shared__ float wts[PN_][16][4];
    __shared__ int   idxs[PN_][16][4];
    __shared__ float accs[16][CO_ + 1];

    if (tid < PN_ * 16) {
        const int p    = tid >> 4;
        const int pixl = tid & 15;
        const float y = loc[(((size_t)b * PN_ + p) * 2 + 0) * HW_ + hw0 + pixl];
        const float x = loc[(((size_t)b * PN_ + p) * 2 + 1) * HW_ + hw0 + pixl];
        const float y0f = floorf(y), x0f = floorf(x);
        const int   y0 = (int)y0f,  x0 = (int)x0f;
        const float dy = y - y0f,   dx = x - x0f;
        const float w[4] = { (1.f - dy) * (1.f - dx), (1.f - dy) * dx,
                             dy * (1.f - dx),         dy * dx };
#pragma unroll
        for (int c = 0; c < 4; ++c) {
            const int yi = y0 + (c >> 1);
            const int xi = x0 + (c & 1);
            const bool valid = (yi >= 0) & (yi < HI_) & (xi >= 0) & (xi < WI_);
            const int yc = min(max(yi, 0), HI_ - 1);
            const int xc = min(max(xi, 0), WI_ - 1);
            wts[p][pixl][c]  = valid ? w[c] : 0.f;
            idxs[p][pixl][c] = yc * WI_ + xc;
        }
    }
    __syncthreads();

    float myacc[5];
    int   cos[5], pixls[5];
#pragma unroll
    for (int k = 0; k < 5; ++k) {
        const int item = tid + (k << 8);
        const int pixl = item / CO_;
        const int co   = item - pixl * CO_;
        cos[k] = co; pixls[k] = pixl;
        myacc[k] = bias[co];
    }
    for (int p = 0; p < PN_; ++p) {
        const float* base = xsrc + ((size_t)b * PN_ + p) * CO_ * (size_t)HW_;
#pragma unroll
        for (int k = 0; k < 5; ++k) {
#pragma unroll
            for (int c = 0; c < 4; ++c) {
                const int   idx = idxs[p][pixls[k]][c];
                const float w   = wts[p][pixls[k]][c];
                myacc[k] = fmaf(base[(size_t)cos[k] * HW_ + idx], w, myacc[k]);
            }
        }
    }
#pragma unroll
    for (int k = 0; k < 5; ++k) accs[pixls[k]][cos[k]] = myacc[k];
    __syncthreads();
    for (int i = tid; i < 16 * CO_; i += 256) {
        const int co  = i >> 4;
        const int hwl = i & 15;
        out[((size_t)b * CO_ + co) * HW_ + hw0 + hwl] = accs[hwl][co];
    }
}

extern "C" void kernel_launch(void* const* d_in, const int* in_sizes, int n_in,
                              void* d_out, int out_size, void* d_ws, size_t ws_size,
                              hipStream_t stream) {
    const float* x    = (const float*)d_in[0];
    const float* loc  = (const float*)d_in[1];
    const float* bias = (const float*)d_in[2];
    float*       out  = (float*)d_out;

    const size_t need = (size_t)B_ * PN_ * HW_ * CO_ * sizeof(uint16_t);   // 94.4 MB
    if (ws_size >= need) {
        uint16_t* xt = (uint16_t*)d_ws;
        // M0: T(0)
        pipe_k<<<dim3(TUNITS), NTHR, 0, stream>>>(x, loc, bias, out, xt, 0, -1);
        // M1..M3: G(i-1) || T(i)   (1664 blocks = 128 groups x 13)
        for (int i = 1; i < B_; ++i)
            pipe_k<<<dim3(TUNITS + GUNITS), NTHR, 0, stream>>>(x, loc, bias, out, xt, i, i - 1);
        // M4: G(3)
        pipe_k<<<dim3(GUNITS), NTHR, 0, stream>>>(x, loc, bias, out, xt, -1, B_ - 1);
    } else {
        gather_direct_k<<<dim3(B_ * HW_ / 16), 256, 0, stream>>>(x, loc, bias, out);
    }
}

// Round 8
// 152.709 us; speedup vs baseline: 1.2509x; 1.2509x over previous
//
#include <hip/hip_runtime.h>
#include <cstddef>
#include <cstdint>

// CollectMerge: x (B, P*CO, HI, WI) fp32, loc (B, 2P, HO, WO) fp32, bias (CO) fp32
// -> out (B, CO, HO, WO) fp32. Bilinear-sample each of P planes at loc, sum over P, + bias.
constexpr int B_  = 4;
constexpr int CO_ = 80;
constexpr int PN_ = 9;
constexpr int HI_ = 128;
constexpr int WI_ = 128;
constexpr int HW_ = HI_ * WI_;   // 16384

__device__ __forceinline__ uint16_t f2bf(float f) {
    uint32_t u = __float_as_uint(f);
    return (uint16_t)((u + 0x7fffu + ((u >> 16) & 1u)) >> 16);   // RNE
}

// ---------------------------------------------------------------------------
// Kernel 1 (exact r2 unit, per-batch grid): transpose+downconvert one batch:
// x (b, CO, HW) fp32 -> xt (b, HW, CO) bf16. grid = (HW/128, PN).
// ---------------------------------------------------------------------------
__global__ __launch_bounds__(256) void transpose_bf16_k(const float* __restrict__ x,
                                                        uint16_t* __restrict__ xt,
                                                        int b) {
    const int bp  = b * PN_ + blockIdx.y;
    const int hw0 = blockIdx.x << 7;               // 128 hw positions per block

    __shared__ uint16_t tile[CO_][136];            // 272B row stride, 16B-aligned

    const float* src = x + (size_t)bp * CO_ * HW_ + hw0;
    for (int i = threadIdx.x; i < CO_ * 32; i += 256) {
        const int co = i >> 5;
        const int h4 = (i & 31) << 2;
        const float4 v = *(const float4*)(src + (size_t)co * HW_ + h4);
        ushort4 pk;
        pk.x = f2bf(v.x); pk.y = f2bf(v.y); pk.z = f2bf(v.z); pk.w = f2bf(v.w);
        *(ushort4*)&tile[co][h4] = pk;
    }
    __syncthreads();

    uint32_t* dst = (uint32_t*)(xt + ((size_t)bp * HW_ + hw0) * CO_);
    for (int i = threadIdx.x; i < 128 * 10; i += 256) {
        const int px = i / 10;
        const int cp = i - px * 10;
        uint4 wv;
        uint32_t* w = (uint32_t*)&wv;
#pragma unroll
        for (int j = 0; j < 4; ++j) {
            const uint32_t lo = tile[cp * 8 + 2 * j][px];
            const uint32_t hi = tile[cp * 8 + 2 * j + 1][px];
            w[j] = lo | (hi << 16);
        }
        *(uint4*)(dst + px * 40 + cp * 4) = wv;
    }
}

// ---------------------------------------------------------------------------
// Kernel 2 (exact r2 unit, per-batch grid): gather + merge one batch.
// grid = 512 blocks (all co-resident -> plane-lockstep p progression).
// ---------------------------------------------------------------------------
__global__ __launch_bounds__(320) void gather_bf16_k(const uint16_t* __restrict__ xt,
                                                     const float* __restrict__ loc,
                                                     const float* __restrict__ bias,
                                                     float* __restrict__ out,
                                                     int b) {
    const int hw0 = blockIdx.x << 5;   // 32 pixels per block
    const int tid = threadIdx.x;

    __shared__ float wts[PN_][32][4];
    __shared__ int   offs[PN_][32][4];
    __shared__ float accs[32][CO_ + 1];        // odd stride -> conflict-free col reads

    // Phase A: bilinear weights + premultiplied byte offsets per (p, pixel)
    if (tid < PN_ * 32) {
        const int p    = tid >> 5;
        const int pixl = tid & 31;
        const float y = loc[(((size_t)b * PN_ + p) * 2 + 0) * HW_ + hw0 + pixl];
        const float x = loc[(((size_t)b * PN_ + p) * 2 + 1) * HW_ + hw0 + pixl];
        const float y0f = floorf(y), x0f = floorf(x);
        const int   y0 = (int)y0f,  x0 = (int)x0f;
        const float dy = y - y0f,   dx = x - x0f;
        const float w[4] = { (1.f - dy) * (1.f - dx), (1.f - dy) * dx,
                             dy * (1.f - dx),         dy * dx };
#pragma unroll
        for (int c = 0; c < 4; ++c) {
            const int yi = y0 + (c >> 1);
            const int xi = x0 + (c & 1);
            const bool valid = (yi >= 0) & (yi < HI_) & (xi >= 0) & (xi < WI_);
            const int yc = min(max(yi, 0), HI_ - 1);
            const int xc = min(max(xi, 0), WI_ - 1);
            wts[p][pixl][c]  = valid ? w[c] : 0.f;
            offs[p][pixl][c] = (yc * WI_ + xc) * (CO_ * 2);   // byte offset
        }
    }
    __syncthreads();

    // Phase B: thread (pixl, cg): pixel pixl, channels cg*8..cg*8+7, 16B load per tap
    const int pixl = tid / 10;
    const int cg   = tid - pixl * 10;

    float acc[8];
#pragma unroll
    for (int j = 0; j < 8; ++j) acc[j] = bias[cg * 8 + j];

    for (int p = 0; p < PN_; ++p) {
        const char* base = (const char*)(xt + ((size_t)b * PN_ + p) * (size_t)HW_ * CO_)
                           + cg * 16;
        uint4 v[4]; float w[4];
#pragma unroll
        for (int c = 0; c < 4; ++c) {
            v[c] = *(const uint4*)(base + offs[p][pixl][c]);
            w[c] = wts[p][pixl][c];
        }
#pragma unroll
        for (int c = 0; c < 4; ++c) {
            const uint32_t* uu = (const uint32_t*)&v[c];
#pragma unroll
            for (int j = 0; j < 4; ++j) {
                acc[2*j]   = fmaf(__uint_as_float(uu[j] << 16),         w[c], acc[2*j]);
                acc[2*j+1] = fmaf(__uint_as_float(uu[j] & 0xffff0000u), w[c], acc[2*j+1]);
            }
        }
    }

#pragma unroll
    for (int j = 0; j < 8; ++j) accs[pixl][cg * 8 + j] = acc[j];
    __syncthreads();

    // Phase C: coalesced channel-major write (32 consecutive hw per co row)
    for (int i = tid; i < 32 * CO_; i += 320) {
        const int co  = i >> 5;
        const int hwl = i & 31;
        out[((size_t)b * CO_ + co) * HW_ + hw0 + hwl] = accs[hwl][co];
    }
}

// ---------------------------------------------------------------------------
// Fallback (workspace too small): direct fp32 gather on original layout.
// ---------------------------------------------------------------------------
__global__ __launch_bounds__(256) void gather_direct_k(const float* __restrict__ xsrc,
                                                       const float* __restrict__ loc,
                                                       const float* __restrict__ bias,
                                                       float* __restrict__ out) {
    const int b   = blockIdx.x >> 10;
    const int hw0 = (blockIdx.x & 1023) << 4;
    const int tid = threadIdx.x;

    __shared__ float wts[PN_][16][4];
    __shared__ int   idxs[PN_][16][4];
    __shared__ float accs[16][CO_ + 1];

    if (tid < PN_ * 16) {
        const int p    = tid >> 4;
        const int pixl = tid & 15;
        const float y = loc[(((size_t)b * PN_ + p) * 2 + 0) * HW_ + hw0 + pixl];
        const float x = loc[(((size_t)b * PN_ + p) * 2 + 1) * HW_ + hw0 + pixl];
        const float y0f = floorf(y), x0f = floorf(x);
        const int   y0 = (int)y0f,  x0 = (int)x0f;
        const float dy = y - y0f,   dx = x - x0f;
        const float w[4] = { (1.f - dy) * (1.f - dx), (1.f - dy) * dx,
                             dy * (1.f - dx),         dy * dx };
#pragma unroll
        for (int c = 0; c < 4; ++c) {
            const int yi = y0 + (c >> 1);
            const int xi = x0 + (c & 1);
            const bool valid = (yi >= 0) & (yi < HI_) & (xi >= 0) & (xi < WI_);
            const int yc = min(max(yi, 0), HI_ - 1);
            const int xc = min(max(xi, 0), WI_ - 1);
            wts[p][pixl][c]  = valid ? w[c] : 0.f;
            idxs[p][pixl][c] = yc * WI_ + xc;
        }
    }
    __syncthreads();

    float myacc[5];
    int   cos[5], pixls[5];
#pragma unroll
    for (int k = 0; k < 5; ++k) {
        const int item = tid + (k << 8);
        const int pixl = item / CO_;
        const int co   = item - pixl * CO_;
        cos[k] = co; pixls[k] = pixl;
        myacc[k] = bias[co];
    }
    for (int p = 0; p < PN_; ++p) {
        const float* base = xsrc + ((size_t)b * PN_ + p) * CO_ * (size_t)HW_;
#pragma unroll
        for (int k = 0; k < 5; ++k) {
#pragma unroll
            for (int c = 0; c < 4; ++c) {
                const int   idx = idxs[p][pixls[k]][c];
                const float w   = wts[p][pixls[k]][c];
                myacc[k] = fmaf(base[(size_t)cos[k] * HW_ + idx], w, myacc[k]);
            }
        }
    }
#pragma unroll
    for (int k = 0; k < 5; ++k) accs[pixls[k]][cos[k]] = myacc[k];
    __syncthreads();
    for (int i = tid; i < 16 * CO_; i += 256) {
        const int co  = i >> 4;
        const int hwl = i & 15;
        out[((size_t)b * CO_ + co) * HW_ + hw0 + hwl] = accs[hwl][co];
    }
}

extern "C" void kernel_launch(void* const* d_in, const int* in_sizes, int n_in,
                              void* d_out, int out_size, void* d_ws, size_t ws_size,
                              hipStream_t stream) {
    const float* x    = (const float*)d_in[0];
    const float* loc  = (const float*)d_in[1];
    const float* bias = (const float*)d_in[2];
    float*       out  = (float*)d_out;

    const size_t need = (size_t)B_ * PN_ * HW_ * CO_ * sizeof(uint16_t);   // 94.4 MB
    if (ws_size >= need) {
        uint16_t* xt = (uint16_t*)d_ws;
        // Fully serial per-batch interleave: G(b) reads xt(b) while it is the
        // freshest 23.6 MB in L3 (<=70 MB written since) -> max residency.
        for (int b = 0; b < B_; ++b) {
            transpose_bf16_k<<<dim3(HW_ / 128, PN_), 256, 0, stream>>>(x, xt, b);
            gather_bf16_k<<<dim3(HW_ / 32), 320, 0, stream>>>(xt, loc, bias, out, b);
        }
    } else {
        gather_direct_k<<<dim3(B_ * HW_ / 16), 256, 0, stream>>>(x, loc, bias, out);
    }
}

// Round 9
// 124.902 us; speedup vs baseline: 1.5294x; 1.2226x over previous
//
#include <hip/hip_runtime.h>
#include <cstddef>
#include <cstdint>

// CollectMerge: x (B, P*CO, HI, WI) fp32, loc (B, 2P, HO, WO) fp32, bias (CO) fp32
// -> out (B, CO, HO, WO) fp32. Bilinear-sample each of P planes at loc, sum over P, + bias.
//
// Final structure (r2, best of 8 rounds): serial two-pass.
//  Pass 1: transpose+bf16-downconvert x -> xt (channel-last). HBM-bound, ~46 us.
//  Pass 2: random bilinear gather of 160B channel chunks + merge. Fabric-bound
//          (~7 TB/s XCD<->IC line traffic), ~65 us.
// All overlap/reorder variants (mixed grids r5/r7, reversed T order r6,
// per-batch interleave r8) measured WORSE: both passes share the XCD<->fabric
// links, and concurrency thrashes L3. This is the structural roofline.
constexpr int B_  = 4;
constexpr int CO_ = 80;
constexpr int PN_ = 9;
constexpr int HI_ = 128;
constexpr int WI_ = 128;
constexpr int HW_ = HI_ * WI_;   // 16384

__device__ __forceinline__ uint16_t f2bf(float f) {
    uint32_t u = __float_as_uint(f);
    return (uint16_t)((u + 0x7fffu + ((u >> 16) & 1u)) >> 16);   // RNE
}

// ---------------------------------------------------------------------------
// Kernel 1: transpose+downconvert x (B*P, CO, HW) fp32 -> xt (B*P, HW, CO) bf16.
// float4 global reads, ushort4 LDS writes, dwordx4 global writes.
// ---------------------------------------------------------------------------
__global__ __launch_bounds__(256) void transpose_bf16_k(const float* __restrict__ x,
                                                        uint16_t* __restrict__ xt) {
    const int bp  = blockIdx.y;          // 0 .. B*P-1
    const int hw0 = blockIdx.x << 7;     // 128 hw positions per block

    // row stride 136 u16 = 272B (16B-aligned rows; ds_write_b64 2-way conflicts = free)
    __shared__ uint16_t tile[CO_][136];

    const float* src = x + (size_t)bp * CO_ * HW_ + hw0;
    // read: 80 co x 32 float4 (=128 hw), 10 per thread
    for (int i = threadIdx.x; i < CO_ * 32; i += 256) {
        const int co = i >> 5;
        const int h4 = (i & 31) << 2;
        const float4 v = *(const float4*)(src + (size_t)co * HW_ + h4);
        ushort4 pk;
        pk.x = f2bf(v.x); pk.y = f2bf(v.y); pk.z = f2bf(v.z); pk.w = f2bf(v.w);
        *(ushort4*)&tile[co][h4] = pk;
    }
    __syncthreads();

    // write: 128 px x 10 dwordx4 (=160B of channels each), 5 per thread
    uint32_t* dst = (uint32_t*)(xt + ((size_t)bp * HW_ + hw0) * CO_);
    for (int i = threadIdx.x; i < 128 * 10; i += 256) {
        const int px = i / 10;
        const int cp = i - px * 10;
        uint4 wv;
        uint32_t* w = (uint32_t*)&wv;
#pragma unroll
        for (int j = 0; j < 4; ++j) {
            const uint32_t lo = tile[cp * 8 + 2 * j][px];
            const uint32_t hi = tile[cp * 8 + 2 * j + 1][px];
            w[j] = lo | (hi << 16);
        }
        *(uint4*)(dst + px * 40 + cp * 4) = wv;
    }
}

// ---------------------------------------------------------------------------
// Kernel 2: gather + merge on bf16 channel-last xt.
// Block = 320 threads, 32 output pixels. Thread (pixl, cg): 8 channels via one
// 16B load per tap (10 lanes cover a 160B sample chunk, coalesced).
// ---------------------------------------------------------------------------
__global__ __launch_bounds__(320) void gather_bf16_k(const uint16_t* __restrict__ xt,
                                                     const float* __restrict__ loc,
                                                     const float* __restrict__ bias,
                                                     float* __restrict__ out) {
    const int b   = blockIdx.x >> 9;           // HW/32 = 512 blocks per batch
    const int hw0 = (blockIdx.x & 511) << 5;   // 32 pixels per block
    const int tid = threadIdx.x;

    __shared__ float wts[PN_][32][4];
    __shared__ int   offs[PN_][32][4];
    __shared__ float accs[32][CO_ + 1];        // stride 81: odd -> conflict-free col reads

    // Phase A: bilinear weights + premultiplied byte offsets per (p, pixel)
    if (tid < PN_ * 32) {
        const int p    = tid >> 5;
        const int pixl = tid & 31;
        const float y = loc[(((size_t)b * PN_ + p) * 2 + 0) * HW_ + hw0 + pixl];
        const float x = loc[(((size_t)b * PN_ + p) * 2 + 1) * HW_ + hw0 + pixl];
        const float y0f = floorf(y), x0f = floorf(x);
        const int   y0 = (int)y0f,  x0 = (int)x0f;
        const float dy = y - y0f,   dx = x - x0f;
        const float w[4] = { (1.f - dy) * (1.f - dx), (1.f - dy) * dx,
                             dy * (1.f - dx),         dy * dx };
#pragma unroll
        for (int c = 0; c < 4; ++c) {
            const int yi = y0 + (c >> 1);
            const int xi = x0 + (c & 1);
            const bool valid = (yi >= 0) & (yi < HI_) & (xi >= 0) & (xi < WI_);
            const int yc = min(max(yi, 0), HI_ - 1);
            const int xc = min(max(xi, 0), WI_ - 1);
            wts[p][pixl][c]  = valid ? w[c] : 0.f;
            offs[p][pixl][c] = (yc * WI_ + xc) * (CO_ * 2);   // byte offset
        }
    }
    __syncthreads();

    // Phase B: thread owns (pixl, cg): pixel pixl, channels cg*8 .. cg*8+7
    const int pixl = tid / 10;
    const int cg   = tid - pixl * 10;

    float acc[8];
#pragma unroll
    for (int j = 0; j < 8; ++j) acc[j] = bias[cg * 8 + j];

    for (int p = 0; p < PN_; ++p) {
        const char* base = (const char*)(xt + ((size_t)b * PN_ + p) * (size_t)HW_ * CO_)
                           + cg * 16;
        uint4 v[4]; float w[4];
#pragma unroll
        for (int c = 0; c < 4; ++c) {
            v[c] = *(const uint4*)(base + offs[p][pixl][c]);
            w[c] = wts[p][pixl][c];
        }
#pragma unroll
        for (int c = 0; c < 4; ++c) {
            const uint32_t* uu = (const uint32_t*)&v[c];
#pragma unroll
            for (int j = 0; j < 4; ++j) {
                acc[2*j]   = fmaf(__uint_as_float(uu[j] << 16),         w[c], acc[2*j]);
                acc[2*j+1] = fmaf(__uint_as_float(uu[j] & 0xffff0000u), w[c], acc[2*j+1]);
            }
        }
    }

#pragma unroll
    for (int j = 0; j < 8; ++j) accs[pixl][cg * 8 + j] = acc[j];
    __syncthreads();

    // Phase C: coalesced channel-major write (32 consecutive hw per co row)
    for (int i = tid; i < 32 * CO_; i += 320) {
        const int co  = i >> 5;
        const int hwl = i & 31;
        out[((size_t)b * CO_ + co) * HW_ + hw0 + hwl] = accs[hwl][co];
    }
}

// ---------------------------------------------------------------------------
// Fallback (workspace too small): direct fp32 gather on original layout.
// ---------------------------------------------------------------------------
__global__ __launch_bounds__(256) void gather_direct_k(const float* __restrict__ xsrc,
                                                       const float* __restrict__ loc,
                                                       const float* __restrict__ bias,
                                                       float* __restrict__ out) {
    const int b   = blockIdx.x >> 10;
    const int hw0 = (blockIdx.x & 1023) << 4;
    const int tid = threadIdx.x;

    __shared__ float wts[PN_][16][4];
    __shared__ int   idxs[PN_][16][4];
    __shared__ float accs[16][CO_ + 1];

    if (tid < PN_ * 16) {
        const int p    = tid >> 4;
        const int pixl = tid & 15;
        const float y = loc[(((size_t)b * PN_ + p) * 2 + 0) * HW_ + hw0 + pixl];
        const float x = loc[(((size_t)b * PN_ + p) * 2 + 1) * HW_ + hw0 + pixl];
        const float y0f = floorf(y), x0f = floorf(x);
        const int   y0 = (int)y0f,  x0 = (int)x0f;
        const float dy = y - y0f,   dx = x - x0f;
        const float w[4] = { (1.f - dy) * (1.f - dx), (1.f - dy) * dx,
                             dy * (1.f - dx),         dy * dx };
#pragma unroll
        for (int c = 0; c < 4; ++c) {
            const int yi = y0 + (c >> 1);
            const int xi = x0 + (c & 1);
            const bool valid = (yi >= 0) & (yi < HI_) & (xi >= 0) & (xi < WI_);
            const int yc = min(max(yi, 0), HI_ - 1);
            const int xc = min(max(xi, 0), WI_ - 1);
            wts[p][pixl][c]  = valid ? w[c] : 0.f;
            idxs[p][pixl][c] = yc * WI_ + xc;
        }
    }
    __syncthreads();

    float myacc[5];
    int   cos[5], pixls[5];
#pragma unroll
    for (int k = 0; k < 5; ++k) {
        const int item = tid + (k << 8);
        const int pixl = item / CO_;
        const int co   = item - pixl * CO_;
        cos[k] = co; pixls[k] = pixl;
        myacc[k] = bias[co];
    }
    for (int p = 0; p < PN_; ++p) {
        const float* base = xsrc + ((size_t)b * PN_ + p) * CO_ * (size_t)HW_;
#pragma unroll
        for (int k = 0; k < 5; ++k) {
#pragma unroll
            for (int c = 0; c < 4; ++c) {
                const int   idx = idxs[p][pixls[k]][c];
                const float w   = wts[p][pixls[k]][c];
                myacc[k] = fmaf(base[(size_t)cos[k] * HW_ + idx], w, myacc[k]);
            }
        }
    }
#pragma unroll
    for (int k = 0; k < 5; ++k) accs[pixls[k]][cos[k]] = myacc[k];
    __syncthreads();
    for (int i = tid; i < 16 * CO_; i += 256) {
        const int co  = i >> 4;
        const int hwl = i & 15;
        out[((size_t)b * CO_ + co) * HW_ + hw0 + hwl] = accs[hwl][co];
    }
}

extern "C" void kernel_launch(void* const* d_in, const int* in_sizes, int n_in,
                              void* d_out, int out_size, void* d_ws, size_t ws_size,
                              hipStream_t stream) {
    const float* x    = (const float*)d_in[0];
    const float* loc  = (const float*)d_in[1];
    const float* bias = (const float*)d_in[2];
    float*       out  = (float*)d_out;

    const size_t need = (size_t)B_ * PN_ * HW_ * CO_ * sizeof(uint16_t);   // 94.4 MB
    if (ws_size >= need) {
        uint16_t* xt = (uint16_t*)d_ws;
        dim3 g1(HW_ / 128, B_ * PN_);
        transpose_bf16_k<<<g1, 256, 0, stream>>>(x, xt);
        gather_bf16_k<<<dim3(B_ * HW_ / 32), 320, 0, stream>>>(xt, loc, bias, out);
    } else {
        gather_direct_k<<<dim3(B_ * HW_ / 16), 256, 0, stream>>>(x, loc, bias, out);
    }
}